// Round 10
// baseline (834.760 us; speedup 1.0000x reference)
//
#include <hip/hip_runtime.h>
#include <hip/hip_bf16.h>

// Problem dims (compile-time)
#define BDIM 4
#define SDIM 2048
#define DDIM 1024
#define HDIM 16
#define FFDIM 4096
#define MROWS (BDIM*SDIM)   // 8192

using bf16 = __hip_bfloat16;
typedef __attribute__((ext_vector_type(8))) short short8;
typedef __attribute__((ext_vector_type(4))) short short4v;
typedef __attribute__((ext_vector_type(4))) float f32x4;

__device__ __forceinline__ f32x4 mfma16(short8 a, short8 b, f32x4 c) {
  return __builtin_amdgcn_mfma_f32_16x16x32_bf16(a, b, c, 0, 0, 0);
}

__device__ __forceinline__ void gll16(const void* g, void* l) {
  __builtin_amdgcn_global_load_lds((const __attribute__((address_space(1))) void*)g,
                                   (__attribute__((address_space(3))) void*)l, 16, 0, 0);
}

// ---------------------------------------------------------------------------
// GEMM: C[M,N] = A[M,K](bf16) * Bt[N,K]^T(bf16) + bias, epilogue variants.
// EPI 0: fp32 row-major out.  EPI 1: QKV scatter -> bf16 [3,B,H,S,64],
//        Q slab pre-scaled by 0.125 (exact, pow2), V slab TRANSPOSED [B,H,64,S].
// EPI 2: GELU (tanh form) -> bf16 row-major out.
// 128x128 tile, BK=32, 256 threads (4 waves, 2x2).
// DOUBLE-BUFFERED staging (2-phase): tile kt+1 issued into alternate LDS
// buffer before computing kt; ONE barrier per K-step (drains staging whose
// latency was hidden under compute). Same hazard structure as attn dbuf (R9 win).
// LDS swizzle: stored[row][slot] = src[row][slot ^ ((row>>1)&3)] (16B slots).
// ---------------------------------------------------------------------------
template<int EPI>
__global__ __launch_bounds__(256)
void gemm_bt(const bf16* __restrict__ A, const bf16* __restrict__ Bt,
             const float* __restrict__ bias0, const float* __restrict__ bias1,
             const float* __restrict__ bias2,
             void* __restrict__ Cout, int K, int N)
{
  __shared__ bf16 As[2][128*32];
  __shared__ bf16 Bs[2][128*32];
  const int tid  = threadIdx.x;
  const int wave = tid >> 6;
  const int lane = tid & 63;
  const int llo  = lane & 15, lhi = lane >> 4;
  const int row0 = blockIdx.y * 128;
  const int col0 = blockIdx.x * 128;
  const int wm = wave >> 1, wn = wave & 1;

  f32x4 acc[4][4];
#pragma unroll
  for (int i = 0; i < 4; i++)
#pragma unroll
    for (int j = 0; j < 4; j++) acc[i][j] = (f32x4){0.f, 0.f, 0.f, 0.f};

  const int c0 = wave * 2, c1 = wave * 2 + 1;
  const size_t arow0 = (size_t)(row0 + c0*16 + (lane >> 2)) * K;
  const size_t arow1 = (size_t)(row0 + c1*16 + (lane >> 2)) * K;
  const size_t brow0 = (size_t)(col0 + c0*16 + (lane >> 2)) * K;
  const size_t brow1 = (size_t)(col0 + c1*16 + (lane >> 2)) * K;
  // pre-swizzled source col16: slot (l&3) holds src col16 (l&3)^((row>>1)&3)
  const int colb = ((lane & 3) ^ ((lane >> 3) & 3)) * 8;

  const int nkt = K >> 5;
  // prologue: stage K-tile 0 into buffer 0
  gll16(A  + arow0 + colb, As[0] + c0*512);
  gll16(A  + arow1 + colb, As[0] + c1*512);
  gll16(Bt + brow0 + colb, Bs[0] + c0*512);
  gll16(Bt + brow1 + colb, Bs[0] + c1*512);
  __syncthreads();

  for (int kt = 0; kt < nkt; ++kt) {
    const int cur = kt & 1;
    if (kt + 1 < nkt) {
      const int kofs = (kt + 1) * 32 + colb;
      gll16(A  + arow0 + kofs, As[cur^1] + c0*512);
      gll16(A  + arow1 + kofs, As[cur^1] + c1*512);
      gll16(Bt + brow0 + kofs, Bs[cur^1] + c0*512);
      gll16(Bt + brow1 + kofs, Bs[cur^1] + c1*512);
    }
    short8 af[4], bfr[4];
    const int rsw = (lhi ^ ((llo >> 1) & 3)) * 8;   // swizzled read slot
#pragma unroll
    for (int mi = 0; mi < 4; mi++)
      af[mi] = *(const short8*)(As[cur] + (wm*64 + mi*16 + llo)*32 + rsw);
#pragma unroll
    for (int ni = 0; ni < 4; ni++)
      bfr[ni] = *(const short8*)(Bs[cur] + (wn*64 + ni*16 + llo)*32 + rsw);
#pragma unroll
    for (int mi = 0; mi < 4; mi++)
#pragma unroll
      for (int ni = 0; ni < 4; ni++)
        acc[mi][ni] = mfma16(af[mi], bfr[ni], acc[mi][ni]);
    __syncthreads();   // drains next-tile staging; protects buffer reuse
  }

#pragma unroll
  for (int mi = 0; mi < 4; mi++) {
#pragma unroll
    for (int ni = 0; ni < 4; ni++) {
      const int col = col0 + wn*64 + ni*16 + llo;
      float bv;
      if (EPI == 1) {
        const int which = col >> 10, win = col & 1023;
        const float* bp = (which == 0) ? bias0 : ((which == 1) ? bias1 : bias2);
        bv = bp[win];
      } else {
        bv = bias0[col];
      }
      if (EPI == 1) {
        const int which = col >> 10, win = col & 1023;
        const int h = win >> 6, dh = win & 63;
        if (which < 2) {
#pragma unroll
          for (int r = 0; r < 4; r++) {
            const int row = row0 + wm*64 + mi*16 + lhi*4 + r;
            const int b = row >> 11, s = row & 2047;
            float v = acc[mi][ni][r] + bv;
            if (which == 0) v *= 0.125f;   // fold 1/sqrt(DH) into Q (exact pow2)
            ((bf16*)Cout)[((((size_t)which*BDIM + b)*HDIM + h)*SDIM + s)*64 + dh] =
                __float2bfloat16(v);
          }
        } else {
          // V slab -> transposed [B,H,64,S]; 4 consecutive s per lane
          const int row = row0 + wm*64 + mi*16 + lhi*4;
          const int b = row >> 11, s = row & 2047;
          short4v pk;
#pragma unroll
          for (int r = 0; r < 4; r++) {
            bf16 t = __float2bfloat16(acc[mi][ni][r] + bv);
            pk[r] = *(short*)&t;
          }
          bf16* vt = (bf16*)Cout + (size_t)2*BDIM*HDIM*SDIM*64;
          *(short4v*)(vt + (((size_t)b*HDIM + h)*64 + dh)*SDIM + s) = pk;
        }
      } else {
#pragma unroll
        for (int r = 0; r < 4; r++) {
          const int row = row0 + wm*64 + mi*16 + lhi*4 + r;
          float v = acc[mi][ni][r] + bv;
          if (EPI == 0) {
            ((float*)Cout)[(size_t)row * N + col] = v;
          } else {
            // GELU, tanh form: 0.5v(1+tanh(u)) = v / (1 + e^{-2u}),
            // u = 0.79788456v(1+0.044715v^2). |err vs exact erf-GELU| <~1e-3.
            float u  = 0.79788456080286536f * v * (1.f + 0.044715f * v * v);
            float gl = v / (1.f + __expf(-2.f * u));
            ((bf16*)Cout)[(size_t)row * N + col] = __float2bfloat16(gl);
          }
        }
      }
    }
  }
}

// ---------------------------------------------------------------------------
// Flash attention fwd. grid = (S/128, B*H), 512 threads (8 waves).
// QBLK=128, KBLK=64, double-buffered K/V staging (R9), defer-max (T13, THR=8),
// s_setprio around MFMA clusters (T5), packed-bit mask applied after exp.
// ---------------------------------------------------------------------------
__global__ __launch_bounds__(512)
void attn_fwd(const bf16* __restrict__ qkv,
              const unsigned long long* __restrict__ mbits,
              bf16* __restrict__ Obuf)
{
  __shared__ bf16 Ks[2][64*64];   // [buf][key][dh], swizzled slots
  __shared__ bf16 Vs[2][64*64];   // [buf][dh][key], swizzled slots
  __shared__ bf16 Ps[8][16*64];   // per-wave P tile, swizzled slots

  const int tid  = threadIdx.x;
  const int wave = tid >> 6, lane = tid & 63;
  const int llo  = lane & 15, lhi = lane >> 4;
  const int bh = blockIdx.y;
  const int b = bh >> 4, h = bh & 15;
  const int q0 = blockIdx.x * 128;

  const bf16* Qp  = qkv + ((size_t)b*HDIM + h) * (size_t)SDIM * 64;
  const bf16* Kp  = qkv + ((size_t)(BDIM*HDIM) + b*HDIM + h) * (size_t)SDIM * 64;
  const bf16* Vtp = qkv + (size_t)2*BDIM*HDIM*SDIM*64
                        + ((size_t)b*HDIM + h) * (size_t)64 * SDIM;  // [64][S]

  short8 qf[2];
  {
    const bf16* qrow = Qp + (size_t)(q0 + wave*16 + llo) * 64;
    qf[0] = *(const short8*)(qrow + lhi*8);
    qf[1] = *(const short8*)(qrow + 32 + lhi*8);
  }

  f32x4 o[4];
#pragma unroll
  for (int n = 0; n < 4; n++) o[n] = (f32x4){0.f, 0.f, 0.f, 0.f};
  float mrun[4], lrun[4];
#pragma unroll
  for (int r = 0; r < 4; r++) { mrun[r] = -INFINITY; lrun[r] = 0.f; }

  const int srow = lane >> 3;                  // row within 8-row chunk
  const int scol = ((lane & 7) ^ srow) * 8;    // pre-swizzled source col (elems)
  const size_t mrow = ((size_t)b*SDIM + q0 + wave*16 + lhi*4) * 32;
  const int sh0 = 31 - llo, sh1 = 15 - llo;    // sign-mask shift amounts

  // prologue: stage tile 0 into buffer 0
  gll16(Kp + (size_t)(wave*8 + srow)*64 + scol, &Ks[0][wave*512]);
  gll16(Vtp + (size_t)(wave*8 + srow)*SDIM + scol, &Vs[0][wave*512]);
  __syncthreads();

  for (int kt = 0; kt < SDIM/64; ++kt) {
    const int cur = kt & 1;
    // issue next tile's staging into the other buffer
    if (kt + 1 < SDIM/64) {
      const int k1 = (kt + 1) * 64;
      gll16(Kp + (size_t)(k1 + wave*8 + srow)*64 + scol, &Ks[cur^1][wave*512]);
      gll16(Vtp + (size_t)(wave*8 + srow)*SDIM + k1 + scol, &Vs[cur^1][wave*512]);
    }
    // mask bits for this wave's 4 q-rows (broadcast across llo)
    unsigned mlo[4], mhi[4];
#pragma unroll
    for (int r = 0; r < 4; r++) {
      unsigned long long mw = mbits[mrow + (size_t)r*32 + kt];
      mlo[r] = (unsigned)mw; mhi[r] = (unsigned)(mw >> 32);
    }

    // S = Q K^T  (16 q-rows x 64 keys per wave); Q pre-scaled by 1/8
    float sv[4][4];
    __builtin_amdgcn_s_setprio(1);
#pragma unroll
    for (int n = 0; n < 4; n++) {
      const int krow = (n*16 + llo) * 64;
      const int sw   = llo & 7;
      short8 kf0 = *(const short8*)(&Ks[cur][krow + ((lhi ^ sw) * 8)]);
      short8 kf1 = *(const short8*)(&Ks[cur][krow + (((4 | lhi) ^ sw) * 8)]);
      f32x4 z = (f32x4){0.f, 0.f, 0.f, 0.f};
      z = mfma16(qf[0], kf0, z);
      z = mfma16(qf[1], kf1, z);
#pragma unroll
      for (int r = 0; r < 4; r++) sv[n][r] = z[r];
    }
    __builtin_amdgcn_s_setprio(0);
    // online softmax with defer-max (T13, THR=8): skip rescale when the tile
    // max doesn't exceed mrun+8; p then bounded by e^8 (bf16 rel-precision ok).
    float scale[4];
    bool need = false;
#pragma unroll
    for (int r = 0; r < 4; r++) {
      float rm = fmaxf(fmaxf(sv[0][r], sv[1][r]), fmaxf(sv[2][r], sv[3][r]));
      rm = fmaxf(rm, __shfl_xor(rm, 1));
      rm = fmaxf(rm, __shfl_xor(rm, 2));
      rm = fmaxf(rm, __shfl_xor(rm, 4));
      rm = fmaxf(rm, __shfl_xor(rm, 8));
      scale[r] = rm;                 // stash tile max
      need |= (rm > mrun[r] + 8.f);
    }
    if (need) {
#pragma unroll
      for (int r = 0; r < 4; r++) {
        float mnew = fmaxf(mrun[r], scale[r]);
        scale[r] = __expf(mrun[r] - mnew);
        mrun[r] = mnew;
      }
#pragma unroll
      for (int n = 0; n < 4; n++)
#pragma unroll
        for (int r = 0; r < 4; r++) o[n][r] *= scale[r];
    } else {
#pragma unroll
      for (int r = 0; r < 4; r++) scale[r] = 1.f;
    }
    float rsum[4] = {0.f, 0.f, 0.f, 0.f};
#pragma unroll
    for (int n = 0; n < 4; n++)
#pragma unroll
      for (int r = 0; r < 4; r++) {
        float p = __expf(sv[n][r] - mrun[r]);
        const unsigned w = (n & 2) ? mhi[r] : mlo[r];
        const int sx = ((int)(w << ((n & 1) ? sh1 : sh0))) >> 31; // 0 or -1
        p = __uint_as_float(__float_as_uint(p) & (unsigned)sx);
        sv[n][r] = p;
        rsum[r] += p;
      }
#pragma unroll
    for (int r = 0; r < 4; r++) {
      float rs = rsum[r];
      rs += __shfl_xor(rs, 1);
      rs += __shfl_xor(rs, 2);
      rs += __shfl_xor(rs, 4);
      rs += __shfl_xor(rs, 8);
      lrun[r] = lrun[r]*scale[r] + rs;
    }
    // P -> LDS (C-layout -> A-layout), swizzled slots, per-wave region
#pragma unroll
    for (int n = 0; n < 4; n++)
#pragma unroll
      for (int r = 0; r < 4; r++) {
        const int prow = lhi*4 + r;
        const int slot = (n*2 + (llo >> 3)) ^ (prow & 7);
        Ps[wave][prow*64 + slot*8 + (llo & 7)] = __float2bfloat16(sv[n][r]);
      }
    // PV
    __builtin_amdgcn_s_setprio(1);
#pragma unroll
    for (int kk = 0; kk < 2; kk++) {
      const int sl = ((kk*4 + lhi) ^ (llo & 7)) * 8;
      short8 pf = *(const short8*)(&Ps[wave][llo*64 + sl]);
#pragma unroll
      for (int n = 0; n < 4; n++) {
        short8 vf = *(const short8*)(&Vs[cur][(n*16 + llo)*64 + sl]);
        o[n] = mfma16(pf, vf, o[n]);
      }
    }
    __builtin_amdgcn_s_setprio(0);
    __syncthreads();   // drains next-tile staging; protects buffer reuse
  }

#pragma unroll
  for (int n = 0; n < 4; n++)
#pragma unroll
    for (int r = 0; r < 4; r++) {
      float v = o[n][r] / lrun[r];
      const int row = q0 + wave*16 + lhi*4 + r;
      const int col = h*64 + n*16 + llo;
      Obuf[((size_t)b*SDIM + row)*DDIM + col] = __float2bfloat16(v);
    }
}

// ---------------------------------------------------------------------------
// out = resid + LayerNorm(y)*g + b ; optional bf16 copy of out.
// One block (256 thr) per row of 1024.
// ---------------------------------------------------------------------------
template<bool WB>
__global__ __launch_bounds__(256)
void add_ln(const float* __restrict__ resid, const float* __restrict__ y,
            const float* __restrict__ gam, const float* __restrict__ bet,
            float* __restrict__ outf, bf16* __restrict__ outb)
{
  __shared__ float red[4];
  const int row = blockIdx.x;
  const int t = threadIdx.x;
  float4 v = ((const float4*)(y + (size_t)row*DDIM))[t];
  float s = v.x + v.y + v.z + v.w;
#pragma unroll
  for (int off = 1; off < 64; off <<= 1) s += __shfl_xor(s, off);
  if ((t & 63) == 0) red[t >> 6] = s;
  __syncthreads();
  const float mean = (red[0]+red[1]+red[2]+red[3]) * (1.f/DDIM);
  const float dx = v.x-mean, dy = v.y-mean, dz = v.z-mean, dw = v.w-mean;
  float sq = dx*dx + dy*dy + dz*dz + dw*dw;
#pragma unroll
  for (int off = 1; off < 64; off <<= 1) sq += __shfl_xor(sq, off);
  __syncthreads();
  if ((t & 63) == 0) red[t >> 6] = sq;
  __syncthreads();
  const float var = (red[0]+red[1]+red[2]+red[3]) * (1.f/DDIM);
  const float rst = rsqrtf(var + 1e-6f);
  const float4 g  = ((const float4*)gam)[t];
  const float4 bb = ((const float4*)bet)[t];
  const float4 rv = ((const float4*)(resid + (size_t)row*DDIM))[t];
  float4 ov;
  ov.x = rv.x + dx*rst*g.x + bb.x;
  ov.y = rv.y + dy*rst*g.y + bb.y;
  ov.z = rv.z + dz*rst*g.z + bb.z;
  ov.w = rv.w + dw*rst*g.w + bb.w;
  ((float4*)(outf + (size_t)row*DDIM))[t] = ov;
  if (WB) {
    bf16* ob = outb + (size_t)row*DDIM + t*4;
    ob[0] = __float2bfloat16(ov.x);
    ob[1] = __float2bfloat16(ov.y);
    ob[2] = __float2bfloat16(ov.z);
    ob[3] = __float2bfloat16(ov.w);
  }
}

// ---------------------------------------------------------------------------
// Prep kernels
// ---------------------------------------------------------------------------
__global__ __launch_bounds__(256)
void transpose_cast(const float* __restrict__ in, bf16* __restrict__ out,
                    int R, int C)   // out[c][r] = in[r][c]; grid (C/32, R/32)
{
  __shared__ float tile[32][33];
  const int x = threadIdx.x & 31, y = threadIdx.x >> 5;
  const int c0 = blockIdx.x * 32, r0 = blockIdx.y * 32;
#pragma unroll
  for (int i = 0; i < 32; i += 8)
    tile[y + i][x] = in[(size_t)(r0 + y + i)*C + c0 + x];
  __syncthreads();
#pragma unroll
  for (int i = 0; i < 32; i += 8)
    out[(size_t)(c0 + y + i)*R + r0 + x] = __float2bfloat16(tile[x][y + i]);
}

__global__ __launch_bounds__(256)
void cast_to_bf16(const float* __restrict__ in, bf16* __restrict__ out, int n4)
{
  const int i = blockIdx.x * 256 + threadIdx.x;
  if (i < n4) {
    float4 v = ((const float4*)in)[i];
    bf16* o = out + (size_t)i*4;
    o[0] = __float2bfloat16(v.x);
    o[1] = __float2bfloat16(v.y);
    o[2] = __float2bfloat16(v.z);
    o[3] = __float2bfloat16(v.w);
  }
}

// pack mask int32 -> 1 bit per entry; one wave per 64-entry word
__global__ __launch_bounds__(256)
void mask_bits_kernel(const int* __restrict__ mask,
                      unsigned long long* __restrict__ bits)
{
  const int wid = blockIdx.x * 4 + (threadIdx.x >> 6);
  const int lane = threadIdx.x & 63;
  const int m = mask[(size_t)wid * 64 + lane];
  const unsigned long long bal = __ballot(m != 0);
  if (lane == 0) bits[wid] = bal;
}

// ---------------------------------------------------------------------------
// Launch. Workspace layout (bytes), total 209,715,200 (~200 MB):
//   0         xb       16,777,216   [x1b aliases]
//   16777216  Wqkvt     6,291,456
//   23068672  Wot       2,097,152
//   25165824  W1t       8,388,608
//   33554432  W2t       8,388,608
//   41943040  mbits     2,097,152   [ffb (32MB) aliases 41943040..75497472]
//   75497472  qkv      50,331,648   [h1 aliases qkv+obuf; V slab = [B,H,64,S]]
//   125829120 obuf     16,777,216
//   142606336 aproj    33,554,432
//   176160768 x1f      33,554,432
// ---------------------------------------------------------------------------
extern "C" void kernel_launch(void* const* d_in, const int* in_sizes, int n_in,
                              void* d_out, int out_size, void* d_ws, size_t ws_size,
                              hipStream_t stream)
{
  (void)in_sizes; (void)n_in; (void)out_size; (void)ws_size;
  const float* x    = (const float*)d_in[0];
  const int*   mask = (const int*)d_in[1];
  const float* Wq   = (const float*)d_in[2];
  const float* bq   = (const float*)d_in[3];
  const float* Wk   = (const float*)d_in[4];
  const float* bk   = (const float*)d_in[5];
  const float* Wv   = (const float*)d_in[6];
  const float* bv   = (const float*)d_in[7];
  const float* Wo   = (const float*)d_in[8];
  const float* bo   = (const float*)d_in[9];
  const float* ln1g = (const float*)d_in[10];
  const float* ln1b = (const float*)d_in[11];
  const float* W1   = (const float*)d_in[12];
  const float* b1   = (const float*)d_in[13];
  const float* W2   = (const float*)d_in[14];
  const float* b2   = (const float*)d_in[15];
  const float* ln2g = (const float*)d_in[16];
  const float* ln2b = (const float*)d_in[17];
  float* out = (float*)d_out;

  char* ws = (char*)d_ws;
  bf16* xb    = (bf16*)(ws + 0);
  bf16* Wqkvt = (bf16*)(ws + 16777216);
  bf16* Wot   = (bf16*)(ws + 23068672);
  bf16* W1t   = (bf16*)(ws + 25165824);
  bf16* W2t   = (bf16*)(ws + 33554432);
  unsigned long long* mbits = (unsigned long long*)(ws + 41943040);
  bf16* qkv   = (bf16*)(ws + 75497472);
  bf16* obuf  = (bf16*)(ws + 125829120);
  float* aproj = (float*)(ws + 142606336);
  float* x1f   = (float*)(ws + 176160768);
  bf16* x1b = xb;             // alias (xb dead after QKV GEMM)
  bf16* h1  = qkv;            // alias over qkv+obuf (dead after O-proj)
  float* ffb = (float*)(ws + 41943040);  // alias over mbits (dead after attn)

  cast_to_bf16<<<dim3(MROWS*DDIM/4/256), 256, 0, stream>>>(x, xb, MROWS*DDIM/4);
  transpose_cast<<<dim3(32, 32), 256, 0, stream>>>(Wq, Wqkvt, 1024, 1024);
  transpose_cast<<<dim3(32, 32), 256, 0, stream>>>(Wk, Wqkvt + 1024*1024, 1024, 1024);
  transpose_cast<<<dim3(32, 32), 256, 0, stream>>>(Wv, Wqkvt + 2*1024*1024, 1024, 1024);
  transpose_cast<<<dim3(32, 32), 256, 0, stream>>>(Wo, Wot, 1024, 1024);
  transpose_cast<<<dim3(FFDIM/32, 32), 256, 0, stream>>>(W1, W1t, 1024, FFDIM);
  transpose_cast<<<dim3(32, FFDIM/32), 256, 0, stream>>>(W2, W2t, FFDIM, 1024);
  mask_bits_kernel<<<dim3(BDIM*SDIM*SDIM/64/4), 256, 0, stream>>>(mask, mbits);

  // QKV projection: [8192,1024] x [1024,3072]; Q pre-scaled, V transposed
  gemm_bt<1><<<dim3(3072/128, MROWS/128), 256, 0, stream>>>(
      xb, Wqkvt, bq, bk, bv, qkv, 1024, 3072);
  // attention (QBLK=128, 8 waves, double-buffered staging, defer-max)
  attn_fwd<<<dim3(SDIM/128, BDIM*HDIM), 512, 0, stream>>>(qkv, mbits, obuf);
  // O projection -> fp32
  gemm_bt<0><<<dim3(1024/128, MROWS/128), 256, 0, stream>>>(
      obuf, Wot, bo, nullptr, nullptr, aproj, 1024, 1024);
  // x1 = x + LN(attn_out); also bf16 copy for FFN
  add_ln<true><<<dim3(MROWS), 256, 0, stream>>>(x, aproj, ln1g, ln1b, x1f, x1b);
  // FFN1 + GELU -> bf16
  gemm_bt<2><<<dim3(FFDIM/128, MROWS/128), 256, 0, stream>>>(
      x1b, W1t, b1, nullptr, nullptr, h1, 1024, FFDIM);
  // FFN2 -> fp32
  gemm_bt<0><<<dim3(1024/128, MROWS/128), 256, 0, stream>>>(
      h1, W2t, b2, nullptr, nullptr, ffb, FFDIM, 1024);
  // out = x1 + LN(ff)
  add_ln<false><<<dim3(MROWS), 256, 0, stream>>>(x1f, ffb, ln2g, ln2b, out, nullptr);
}

// Round 13
// 793.854 us; speedup vs baseline: 1.0515x; 1.0515x over previous
//
#include <hip/hip_runtime.h>
#include <hip/hip_bf16.h>

// Problem dims (compile-time)
#define BDIM 4
#define SDIM 2048
#define DDIM 1024
#define HDIM 16
#define FFDIM 4096
#define MROWS (BDIM*SDIM)   // 8192

using bf16 = __hip_bfloat16;
typedef __attribute__((ext_vector_type(8))) short short8;
typedef __attribute__((ext_vector_type(4))) short short4v;
typedef __attribute__((ext_vector_type(4))) float f32x4;

__device__ __forceinline__ f32x4 mfma16(short8 a, short8 b, f32x4 c) {
  return __builtin_amdgcn_mfma_f32_16x16x32_bf16(a, b, c, 0, 0, 0);
}

__device__ __forceinline__ void gll16(const void* g, void* l) {
  __builtin_amdgcn_global_load_lds((const __attribute__((address_space(1))) void*)g,
                                   (__attribute__((address_space(3))) void*)l, 16, 0, 0);
}

// ---------------------------------------------------------------------------
// GEMM: C[M,N] = A[M,K](bf16) * Bt[N,K]^T(bf16) + bias, epilogue variants.
// EPI 0: fp32 row-major out.  EPI 1: QKV scatter -> bf16 [3,B,H,S,64],
//        Q slab pre-scaled by 0.125*log2(e) (scores in log2 domain; softmax
//        invariant), V slab TRANSPOSED [B,H,64,S].
// EPI 2: GELU (tanh form, exp2) -> bf16 row-major out.
// 128x128 tile, BK=32, 256 threads (4 waves, 2x2), double-buffered staging.
// LDS swizzle: stored[row][slot] = src[row][slot ^ ((row>>1)&3)] (16B slots).
// ---------------------------------------------------------------------------
template<int EPI>
__global__ __launch_bounds__(256)
void gemm_bt(const bf16* __restrict__ A, const bf16* __restrict__ Bt,
             const float* __restrict__ bias0, const float* __restrict__ bias1,
             const float* __restrict__ bias2,
             void* __restrict__ Cout, int K, int N)
{
  __shared__ bf16 As[2][128*32];
  __shared__ bf16 Bs[2][128*32];
  const int tid  = threadIdx.x;
  const int wave = tid >> 6;
  const int lane = tid & 63;
  const int llo  = lane & 15, lhi = lane >> 4;
  const int row0 = blockIdx.y * 128;
  const int col0 = blockIdx.x * 128;
  const int wm = wave >> 1, wn = wave & 1;

  f32x4 acc[4][4];
#pragma unroll
  for (int i = 0; i < 4; i++)
#pragma unroll
    for (int j = 0; j < 4; j++) acc[i][j] = (f32x4){0.f, 0.f, 0.f, 0.f};

  const int c0 = wave * 2, c1 = wave * 2 + 1;
  const size_t arow0 = (size_t)(row0 + c0*16 + (lane >> 2)) * K;
  const size_t arow1 = (size_t)(row0 + c1*16 + (lane >> 2)) * K;
  const size_t brow0 = (size_t)(col0 + c0*16 + (lane >> 2)) * K;
  const size_t brow1 = (size_t)(col0 + c1*16 + (lane >> 2)) * K;
  // pre-swizzled source col16: slot (l&3) holds src col16 (l&3)^((row>>1)&3)
  const int colb = ((lane & 3) ^ ((lane >> 3) & 3)) * 8;

  const int nkt = K >> 5;
  // prologue: stage K-tile 0 into buffer 0
  gll16(A  + arow0 + colb, As[0] + c0*512);
  gll16(A  + arow1 + colb, As[0] + c1*512);
  gll16(Bt + brow0 + colb, Bs[0] + c0*512);
  gll16(Bt + brow1 + colb, Bs[0] + c1*512);
  __syncthreads();

  for (int kt = 0; kt < nkt; ++kt) {
    const int cur = kt & 1;
    if (kt + 1 < nkt) {
      const int kofs = (kt + 1) * 32 + colb;
      gll16(A  + arow0 + kofs, As[cur^1] + c0*512);
      gll16(A  + arow1 + kofs, As[cur^1] + c1*512);
      gll16(Bt + brow0 + kofs, Bs[cur^1] + c0*512);
      gll16(Bt + brow1 + kofs, Bs[cur^1] + c1*512);
    }
    short8 af[4], bfr[4];
    const int rsw = (lhi ^ ((llo >> 1) & 3)) * 8;   // swizzled read slot
#pragma unroll
    for (int mi = 0; mi < 4; mi++)
      af[mi] = *(const short8*)(As[cur] + (wm*64 + mi*16 + llo)*32 + rsw);
#pragma unroll
    for (int ni = 0; ni < 4; ni++)
      bfr[ni] = *(const short8*)(Bs[cur] + (wn*64 + ni*16 + llo)*32 + rsw);
#pragma unroll
    for (int mi = 0; mi < 4; mi++)
#pragma unroll
      for (int ni = 0; ni < 4; ni++)
        acc[mi][ni] = mfma16(af[mi], bfr[ni], acc[mi][ni]);
    __syncthreads();   // drains next-tile staging; protects buffer reuse
  }

#pragma unroll
  for (int mi = 0; mi < 4; mi++) {
#pragma unroll
    for (int ni = 0; ni < 4; ni++) {
      const int col = col0 + wn*64 + ni*16 + llo;
      float bv;
      if (EPI == 1) {
        const int which = col >> 10, win = col & 1023;
        const float* bp = (which == 0) ? bias0 : ((which == 1) ? bias1 : bias2);
        bv = bp[win];
      } else {
        bv = bias0[col];
      }
      if (EPI == 1) {
        const int which = col >> 10, win = col & 1023;
        const int h = win >> 6, dh = win & 63;
        if (which < 2) {
#pragma unroll
          for (int r = 0; r < 4; r++) {
            const int row = row0 + wm*64 + mi*16 + lhi*4 + r;
            const int b = row >> 11, s = row & 2047;
            float v = acc[mi][ni][r] + bv;
            // fold 1/sqrt(DH) * log2(e) into Q: scores land in log2 domain
            if (which == 0) v *= 0.18033688011112042f;
            ((bf16*)Cout)[((((size_t)which*BDIM + b)*HDIM + h)*SDIM + s)*64 + dh] =
                __float2bfloat16(v);
          }
        } else {
          // V slab -> transposed [B,H,64,S]; 4 consecutive s per lane
          const int row = row0 + wm*64 + mi*16 + lhi*4;
          const int b = row >> 11, s = row & 2047;
          short4v pk;
#pragma unroll
          for (int r = 0; r < 4; r++) {
            bf16 t = __float2bfloat16(acc[mi][ni][r] + bv);
            pk[r] = *(short*)&t;
          }
          bf16* vt = (bf16*)Cout + (size_t)2*BDIM*HDIM*SDIM*64;
          *(short4v*)(vt + (((size_t)b*HDIM + h)*64 + dh)*SDIM + s) = pk;
        }
      } else {
#pragma unroll
        for (int r = 0; r < 4; r++) {
          const int row = row0 + wm*64 + mi*16 + lhi*4 + r;
          float v = acc[mi][ni][r] + bv;
          if (EPI == 0) {
            ((float*)Cout)[(size_t)row * N + col] = v;
          } else {
            // GELU tanh form via exp2: 0.5v(1+tanh(u)) = v / (1 + 2^(-2u*log2e))
            float u  = 0.79788456080286536f * v * (1.f + 0.044715f * v * v);
            float gl = v / (1.f + exp2f(-2.8853900817779268f * u));
            ((bf16*)Cout)[(size_t)row * N + col] = __float2bfloat16(gl);
          }
        }
      }
    }
  }
}

// ---------------------------------------------------------------------------
// Flash attention fwd. grid = (S/128, B*H), 512 threads (8 waves).
// QBLK=128, KBLK=64, double-buffered K/V staging (R9 structure, VGPR=64),
// s_setprio around MFMA clusters, packed-bit mask applied after exp2.
// Scores arrive in log2 domain (Q pre-scaled by 0.125*log2e): all exp -> exp2.
// ---------------------------------------------------------------------------
__global__ __launch_bounds__(512)
void attn_fwd(const bf16* __restrict__ qkv,
              const unsigned long long* __restrict__ mbits,
              bf16* __restrict__ Obuf)
{
  __shared__ bf16 Ks[2][64*64];   // [buf][key][dh], swizzled slots
  __shared__ bf16 Vs[2][64*64];   // [buf][dh][key], swizzled slots
  __shared__ bf16 Ps[8][16*64];   // per-wave P tile, swizzled slots

  const int tid  = threadIdx.x;
  const int wave = tid >> 6, lane = tid & 63;
  const int llo  = lane & 15, lhi = lane >> 4;
  const int bh = blockIdx.y;
  const int b = bh >> 4, h = bh & 15;
  const int q0 = blockIdx.x * 128;

  const bf16* Qp  = qkv + ((size_t)b*HDIM + h) * (size_t)SDIM * 64;
  const bf16* Kp  = qkv + ((size_t)(BDIM*HDIM) + b*HDIM + h) * (size_t)SDIM * 64;
  const bf16* Vtp = qkv + (size_t)2*BDIM*HDIM*SDIM*64
                        + ((size_t)b*HDIM + h) * (size_t)64 * SDIM;  // [64][S]

  short8 qf[2];
  {
    const bf16* qrow = Qp + (size_t)(q0 + wave*16 + llo) * 64;
    qf[0] = *(const short8*)(qrow + lhi*8);
    qf[1] = *(const short8*)(qrow + 32 + lhi*8);
  }

  f32x4 o[4];
#pragma unroll
  for (int n = 0; n < 4; n++) o[n] = (f32x4){0.f, 0.f, 0.f, 0.f};
  float mrun[4], lrun[4];
#pragma unroll
  for (int r = 0; r < 4; r++) { mrun[r] = -INFINITY; lrun[r] = 0.f; }

  const int srow = lane >> 3;                  // row within 8-row chunk
  const int scol = ((lane & 7) ^ srow) * 8;    // pre-swizzled source col (elems)
  const size_t mrow = ((size_t)b*SDIM + q0 + wave*16 + lhi*4) * 32;
  const int sh0 = 31 - llo, sh1 = 15 - llo;    // sign-mask shift amounts

  // prologue: stage tile 0 into buffer 0
  gll16(Kp + (size_t)(wave*8 + srow)*64 + scol, &Ks[0][wave*512]);
  gll16(Vtp + (size_t)(wave*8 + srow)*SDIM + scol, &Vs[0][wave*512]);
  __syncthreads();

  for (int kt = 0; kt < SDIM/64; ++kt) {
    const int cur = kt & 1;
    // issue next tile's staging into the other buffer (latency hides under
    // this tile's compute; drained by the end-of-iteration barrier)
    if (kt + 1 < SDIM/64) {
      const int k1 = (kt + 1) * 64;
      gll16(Kp + (size_t)(k1 + wave*8 + srow)*64 + scol, &Ks[cur^1][wave*512]);
      gll16(Vtp + (size_t)(wave*8 + srow)*SDIM + k1 + scol, &Vs[cur^1][wave*512]);
    }
    // mask bits for this wave's 4 q-rows (broadcast across llo)
    unsigned mlo[4], mhi[4];
#pragma unroll
    for (int r = 0; r < 4; r++) {
      unsigned long long mw = mbits[mrow + (size_t)r*32 + kt];
      mlo[r] = (unsigned)mw; mhi[r] = (unsigned)(mw >> 32);
    }

    // S = Q K^T  (16 q-rows x 64 keys per wave), log2 domain
    float sv[4][4];
    __builtin_amdgcn_s_setprio(1);
#pragma unroll
    for (int n = 0; n < 4; n++) {
      const int krow = (n*16 + llo) * 64;
      const int sw   = llo & 7;
      short8 kf0 = *(const short8*)(&Ks[cur][krow + ((lhi ^ sw) * 8)]);
      short8 kf1 = *(const short8*)(&Ks[cur][krow + (((4 | lhi) ^ sw) * 8)]);
      f32x4 z = (f32x4){0.f, 0.f, 0.f, 0.f};
      z = mfma16(qf[0], kf0, z);
      z = mfma16(qf[1], kf1, z);
#pragma unroll
      for (int r = 0; r < 4; r++) sv[n][r] = z[r];
    }
    __builtin_amdgcn_s_setprio(0);
    // online softmax (log2 domain; masked p zeroed after exp2)
    float mnew[4], scale[4];
#pragma unroll
    for (int r = 0; r < 4; r++) {
      float rm = fmaxf(fmaxf(sv[0][r], sv[1][r]), fmaxf(sv[2][r], sv[3][r]));
      rm = fmaxf(rm, __shfl_xor(rm, 1));
      rm = fmaxf(rm, __shfl_xor(rm, 2));
      rm = fmaxf(rm, __shfl_xor(rm, 4));
      rm = fmaxf(rm, __shfl_xor(rm, 8));
      mnew[r] = fmaxf(mrun[r], rm);
      scale[r] = exp2f(mrun[r] - mnew[r]);
      mrun[r] = mnew[r];
    }
    float rsum[4] = {0.f, 0.f, 0.f, 0.f};
#pragma unroll
    for (int n = 0; n < 4; n++)
#pragma unroll
      for (int r = 0; r < 4; r++) {
        float p = exp2f(sv[n][r] - mnew[r]);
        const unsigned w = (n & 2) ? mhi[r] : mlo[r];
        const int sx = ((int)(w << ((n & 1) ? sh1 : sh0))) >> 31; // 0 or -1
        p = __uint_as_float(__float_as_uint(p) & (unsigned)sx);
        sv[n][r] = p;
        rsum[r] += p;
      }
#pragma unroll
    for (int r = 0; r < 4; r++) {
      float rs = rsum[r];
      rs += __shfl_xor(rs, 1);
      rs += __shfl_xor(rs, 2);
      rs += __shfl_xor(rs, 4);
      rs += __shfl_xor(rs, 8);
      lrun[r] = lrun[r]*scale[r] + rs;
    }
#pragma unroll
    for (int n = 0; n < 4; n++)
#pragma unroll
      for (int r = 0; r < 4; r++) o[n][r] *= scale[r];
    // P -> LDS (C-layout -> A-layout), swizzled slots, per-wave region
#pragma unroll
    for (int n = 0; n < 4; n++)
#pragma unroll
      for (int r = 0; r < 4; r++) {
        const int prow = lhi*4 + r;
        const int slot = (n*2 + (llo >> 3)) ^ (prow & 7);
        Ps[wave][prow*64 + slot*8 + (llo & 7)] = __float2bfloat16(sv[n][r]);
      }
    // PV
    __builtin_amdgcn_s_setprio(1);
#pragma unroll
    for (int kk = 0; kk < 2; kk++) {
      const int sl = ((kk*4 + lhi) ^ (llo & 7)) * 8;
      short8 pf = *(const short8*)(&Ps[wave][llo*64 + sl]);
#pragma unroll
      for (int n = 0; n < 4; n++) {
        short8 vf = *(const short8*)(&Vs[cur][(n*16 + llo)*64 + sl]);
        o[n] = mfma16(pf, vf, o[n]);
      }
    }
    __builtin_amdgcn_s_setprio(0);
    __syncthreads();   // drains next-tile staging; protects buffer reuse
  }

#pragma unroll
  for (int n = 0; n < 4; n++)
#pragma unroll
    for (int r = 0; r < 4; r++) {
      float v = o[n][r] / lrun[r];
      const int row = q0 + wave*16 + lhi*4 + r;
      const int col = h*64 + n*16 + llo;
      Obuf[((size_t)b*SDIM + row)*DDIM + col] = __float2bfloat16(v);
    }
}

// ---------------------------------------------------------------------------
// out = resid + LayerNorm(y)*g + b ; optional bf16 copy of out.
// One block (256 thr) per row of 1024.
// ---------------------------------------------------------------------------
template<bool WB>
__global__ __launch_bounds__(256)
void add_ln(const float* __restrict__ resid, const float* __restrict__ y,
            const float* __restrict__ gam, const float* __restrict__ bet,
            float* __restrict__ outf, bf16* __restrict__ outb)
{
  __shared__ float red[4];
  const int row = blockIdx.x;
  const int t = threadIdx.x;
  float4 v = ((const float4*)(y + (size_t)row*DDIM))[t];
  float s = v.x + v.y + v.z + v.w;
#pragma unroll
  for (int off = 1; off < 64; off <<= 1) s += __shfl_xor(s, off);
  if ((t & 63) == 0) red[t >> 6] = s;
  __syncthreads();
  const float mean = (red[0]+red[1]+red[2]+red[3]) * (1.f/DDIM);
  const float dx = v.x-mean, dy = v.y-mean, dz = v.z-mean, dw = v.w-mean;
  float sq = dx*dx + dy*dy + dz*dz + dw*dw;
#pragma unroll
  for (int off = 1; off < 64; off <<= 1) sq += __shfl_xor(sq, off);
  __syncthreads();
  if ((t & 63) == 0) red[t >> 6] = sq;
  __syncthreads();
  const float var = (red[0]+red[1]+red[2]+red[3]) * (1.f/DDIM);
  const float rst = rsqrtf(var + 1e-6f);
  const float4 g  = ((const float4*)gam)[t];
  const float4 bb = ((const float4*)bet)[t];
  const float4 rv = ((const float4*)(resid + (size_t)row*DDIM))[t];
  float4 ov;
  ov.x = rv.x + dx*rst*g.x + bb.x;
  ov.y = rv.y + dy*rst*g.y + bb.y;
  ov.z = rv.z + dz*rst*g.z + bb.z;
  ov.w = rv.w + dw*rst*g.w + bb.w;
  ((float4*)(outf + (size_t)row*DDIM))[t] = ov;
  if (WB) {
    bf16* ob = outb + (size_t)row*DDIM + t*4;
    ob[0] = __float2bfloat16(ov.x);
    ob[1] = __float2bfloat16(ov.y);
    ob[2] = __float2bfloat16(ov.z);
    ob[3] = __float2bfloat16(ov.w);
  }
}

// ---------------------------------------------------------------------------
// Prep kernels
// ---------------------------------------------------------------------------
__global__ __launch_bounds__(256)
void transpose_cast(const float* __restrict__ in, bf16* __restrict__ out,
                    int R, int C)   // out[c][r] = in[r][c]; grid (C/32, R/32)
{
  __shared__ float tile[32][33];
  const int x = threadIdx.x & 31, y = threadIdx.x >> 5;
  const int c0 = blockIdx.x * 32, r0 = blockIdx.y * 32;
#pragma unroll
  for (int i = 0; i < 32; i += 8)
    tile[y + i][x] = in[(size_t)(r0 + y + i)*C + c0 + x];
  __syncthreads();
#pragma unroll
  for (int i = 0; i < 32; i += 8)
    out[(size_t)(c0 + y + i)*R + r0 + x] = __float2bfloat16(tile[x][y + i]);
}

__global__ __launch_bounds__(256)
void cast_to_bf16(const float* __restrict__ in, bf16* __restrict__ out, int n4)
{
  const int i = blockIdx.x * 256 + threadIdx.x;
  if (i < n4) {
    float4 v = ((const float4*)in)[i];
    bf16* o = out + (size_t)i*4;
    o[0] = __float2bfloat16(v.x);
    o[1] = __float2bfloat16(v.y);
    o[2] = __float2bfloat16(v.z);
    o[3] = __float2bfloat16(v.w);
  }
}

// pack mask int32 -> 1 bit per entry; one wave per 64-entry word
__global__ __launch_bounds__(256)
void mask_bits_kernel(const int* __restrict__ mask,
                      unsigned long long* __restrict__ bits)
{
  const int wid = blockIdx.x * 4 + (threadIdx.x >> 6);
  const int lane = threadIdx.x & 63;
  const int m = mask[(size_t)wid * 64 + lane];
  const unsigned long long bal = __ballot(m != 0);
  if (lane == 0) bits[wid] = bal;
}

// ---------------------------------------------------------------------------
// Launch. Workspace layout (bytes), total 209,715,200 (~200 MB):
//   0         xb       16,777,216   [x1b aliases]
//   16777216  Wqkvt     6,291,456
//   23068672  Wot       2,097,152
//   25165824  W1t       8,388,608
//   33554432  W2t       8,388,608
//   41943040  mbits     2,097,152   [ffb (32MB) aliases 41943040..75497472]
//   75497472  qkv      50,331,648   [h1 aliases qkv+obuf; V slab = [B,H,64,S]]
//   125829120 obuf     16,777,216
//   142606336 aproj    33,554,432
//   176160768 x1f      33,554,432
// ---------------------------------------------------------------------------
extern "C" void kernel_launch(void* const* d_in, const int* in_sizes, int n_in,
                              void* d_out, int out_size, void* d_ws, size_t ws_size,
                              hipStream_t stream)
{
  (void)in_sizes; (void)n_in; (void)out_size; (void)ws_size;
  const float* x    = (const float*)d_in[0];
  const int*   mask = (const int*)d_in[1];
  const float* Wq   = (const float*)d_in[2];
  const float* bq   = (const float*)d_in[3];
  const float* Wk   = (const float*)d_in[4];
  const float* bk   = (const float*)d_in[5];
  const float* Wv   = (const float*)d_in[6];
  const float* bv   = (const float*)d_in[7];
  const float* Wo   = (const float*)d_in[8];
  const float* bo   = (const float*)d_in[9];
  const float* ln1g = (const float*)d_in[10];
  const float* ln1b = (const float*)d_in[11];
  const float* W1   = (const float*)d_in[12];
  const float* b1   = (const float*)d_in[13];
  const float* W2   = (const float*)d_in[14];
  const float* b2   = (const float*)d_in[15];
  const float* ln2g = (const float*)d_in[16];
  const float* ln2b = (const float*)d_in[17];
  float* out = (float*)d_out;

  char* ws = (char*)d_ws;
  bf16* xb    = (bf16*)(ws + 0);
  bf16* Wqkvt = (bf16*)(ws + 16777216);
  bf16* Wot   = (bf16*)(ws + 23068672);
  bf16* W1t   = (bf16*)(ws + 25165824);
  bf16* W2t   = (bf16*)(ws + 33554432);
  unsigned long long* mbits = (unsigned long long*)(ws + 41943040);
  bf16* qkv   = (bf16*)(ws + 75497472);
  bf16* obuf  = (bf16*)(ws + 125829120);
  float* aproj = (float*)(ws + 142606336);
  float* x1f   = (float*)(ws + 176160768);
  bf16* x1b = xb;             // alias (xb dead after QKV GEMM)
  bf16* h1  = qkv;            // alias over qkv+obuf (dead after O-proj)
  float* ffb = (float*)(ws + 41943040);  // alias over mbits (dead after attn)

  cast_to_bf16<<<dim3(MROWS*DDIM/4/256), 256, 0, stream>>>(x, xb, MROWS*DDIM/4);
  transpose_cast<<<dim3(32, 32), 256, 0, stream>>>(Wq, Wqkvt, 1024, 1024);
  transpose_cast<<<dim3(32, 32), 256, 0, stream>>>(Wk, Wqkvt + 1024*1024, 1024, 1024);
  transpose_cast<<<dim3(32, 32), 256, 0, stream>>>(Wv, Wqkvt + 2*1024*1024, 1024, 1024);
  transpose_cast<<<dim3(32, 32), 256, 0, stream>>>(Wo, Wot, 1024, 1024);
  transpose_cast<<<dim3(FFDIM/32, 32), 256, 0, stream>>>(W1, W1t, 1024, FFDIM);
  transpose_cast<<<dim3(32, FFDIM/32), 256, 0, stream>>>(W2, W2t, FFDIM, 1024);
  mask_bits_kernel<<<dim3(BDIM*SDIM*SDIM/64/4), 256, 0, stream>>>(mask, mbits);

  // QKV projection: [8192,1024] x [1024,3072]; Q pre-scaled, V transposed
  gemm_bt<1><<<dim3(3072/128, MROWS/128), 256, 0, stream>>>(
      xb, Wqkvt, bq, bk, bv, qkv, 1024, 3072);
  // attention (QBLK=128, 8 waves, double-buffered staging)
  attn_fwd<<<dim3(SDIM/128, BDIM*HDIM), 512, 0, stream>>>(qkv, mbits, obuf);
  // O projection -> fp32
  gemm_bt<0><<<dim3(1024/128, MROWS/128), 256, 0, stream>>>(
      obuf, Wot, bo, nullptr, nullptr, aproj, 1024, 1024);
  // x1 = x + LN(attn_out); also bf16 copy for FFN
  add_ln<true><<<dim3(MROWS), 256, 0, stream>>>(x, aproj, ln1g, ln1b, x1f, x1b);
  // FFN1 + GELU -> bf16
  gemm_bt<2><<<dim3(FFDIM/128, MROWS/128), 256, 0, stream>>>(
      x1b, W1t, b1, nullptr, nullptr, h1, 1024, FFDIM);
  // FFN2 -> fp32
  gemm_bt<0><<<dim3(1024/128, MROWS/128), 256, 0, stream>>>(
      h1, W2t, b2, nullptr, nullptr, ffb, FFDIM, 1024);
  // out = x1 + LN(ff)
  add_ln<false><<<dim3(MROWS), 256, 0, stream>>>(x1f, ffb, ln2g, ln2b, out, nullptr);
}

// Round 14
// 782.498 us; speedup vs baseline: 1.0668x; 1.0145x over previous
//
#include <hip/hip_runtime.h>
#include <hip/hip_bf16.h>

// Problem dims (compile-time)
#define BDIM 4
#define SDIM 2048
#define DDIM 1024
#define HDIM 16
#define FFDIM 4096
#define MROWS (BDIM*SDIM)   // 8192

using bf16 = __hip_bfloat16;
typedef __attribute__((ext_vector_type(8))) short short8;
typedef __attribute__((ext_vector_type(4))) short short4v;
typedef __attribute__((ext_vector_type(4))) float f32x4;

// 2^x via the raw v_exp_f32 instruction (1 VALU op). exp2f() is the PRECISE
// OCML path (~8 ops, caused R13's +30% VALU); __expf is native but 2 ops.
#if __has_builtin(__builtin_amdgcn_exp2f)
#define EXP2F(x) __builtin_amdgcn_exp2f(x)
#else
#define EXP2F(x) __expf(0.69314718055994531f * (x))
#endif

__device__ __forceinline__ f32x4 mfma16(short8 a, short8 b, f32x4 c) {
  return __builtin_amdgcn_mfma_f32_16x16x32_bf16(a, b, c, 0, 0, 0);
}

__device__ __forceinline__ void gll16(const void* g, void* l) {
  __builtin_amdgcn_global_load_lds((const __attribute__((address_space(1))) void*)g,
                                   (__attribute__((address_space(3))) void*)l, 16, 0, 0);
}

// ---------------------------------------------------------------------------
// GEMM: C[M,N] = A[M,K](bf16) * Bt[N,K]^T(bf16) + bias, epilogue variants.
// EPI 0: fp32 row-major out.  EPI 1: QKV scatter -> bf16 [3,B,H,S,64],
//        Q slab pre-scaled by 0.125*log2(e) (scores in log2 domain; softmax
//        invariant), V slab TRANSPOSED [B,H,64,S].
// EPI 2: GELU (tanh form, exp2) -> bf16 row-major out.
// 128x128 tile, BK=32, 256 threads (4 waves, 2x2), double-buffered staging.
// LDS swizzle: stored[row][slot] = src[row][slot ^ ((row>>1)&3)] (16B slots).
// ---------------------------------------------------------------------------
template<int EPI>
__global__ __launch_bounds__(256)
void gemm_bt(const bf16* __restrict__ A, const bf16* __restrict__ Bt,
             const float* __restrict__ bias0, const float* __restrict__ bias1,
             const float* __restrict__ bias2,
             void* __restrict__ Cout, int K, int N)
{
  __shared__ bf16 As[2][128*32];
  __shared__ bf16 Bs[2][128*32];
  const int tid  = threadIdx.x;
  const int wave = tid >> 6;
  const int lane = tid & 63;
  const int llo  = lane & 15, lhi = lane >> 4;
  const int row0 = blockIdx.y * 128;
  const int col0 = blockIdx.x * 128;
  const int wm = wave >> 1, wn = wave & 1;

  f32x4 acc[4][4];
#pragma unroll
  for (int i = 0; i < 4; i++)
#pragma unroll
    for (int j = 0; j < 4; j++) acc[i][j] = (f32x4){0.f, 0.f, 0.f, 0.f};

  const int c0 = wave * 2, c1 = wave * 2 + 1;
  const size_t arow0 = (size_t)(row0 + c0*16 + (lane >> 2)) * K;
  const size_t arow1 = (size_t)(row0 + c1*16 + (lane >> 2)) * K;
  const size_t brow0 = (size_t)(col0 + c0*16 + (lane >> 2)) * K;
  const size_t brow1 = (size_t)(col0 + c1*16 + (lane >> 2)) * K;
  // pre-swizzled source col16: slot (l&3) holds src col16 (l&3)^((row>>1)&3)
  const int colb = ((lane & 3) ^ ((lane >> 3) & 3)) * 8;

  const int nkt = K >> 5;
  // prologue: stage K-tile 0 into buffer 0
  gll16(A  + arow0 + colb, As[0] + c0*512);
  gll16(A  + arow1 + colb, As[0] + c1*512);
  gll16(Bt + brow0 + colb, Bs[0] + c0*512);
  gll16(Bt + brow1 + colb, Bs[0] + c1*512);
  __syncthreads();

  for (int kt = 0; kt < nkt; ++kt) {
    const int cur = kt & 1;
    if (kt + 1 < nkt) {
      const int kofs = (kt + 1) * 32 + colb;
      gll16(A  + arow0 + kofs, As[cur^1] + c0*512);
      gll16(A  + arow1 + kofs, As[cur^1] + c1*512);
      gll16(Bt + brow0 + kofs, Bs[cur^1] + c0*512);
      gll16(Bt + brow1 + kofs, Bs[cur^1] + c1*512);
    }
    short8 af[4], bfr[4];
    const int rsw = (lhi ^ ((llo >> 1) & 3)) * 8;   // swizzled read slot
#pragma unroll
    for (int mi = 0; mi < 4; mi++)
      af[mi] = *(const short8*)(As[cur] + (wm*64 + mi*16 + llo)*32 + rsw);
#pragma unroll
    for (int ni = 0; ni < 4; ni++)
      bfr[ni] = *(const short8*)(Bs[cur] + (wn*64 + ni*16 + llo)*32 + rsw);
#pragma unroll
    for (int mi = 0; mi < 4; mi++)
#pragma unroll
      for (int ni = 0; ni < 4; ni++)
        acc[mi][ni] = mfma16(af[mi], bfr[ni], acc[mi][ni]);
    __syncthreads();   // drains next-tile staging; protects buffer reuse
  }

#pragma unroll
  for (int mi = 0; mi < 4; mi++) {
#pragma unroll
    for (int ni = 0; ni < 4; ni++) {
      const int col = col0 + wn*64 + ni*16 + llo;
      float bv;
      if (EPI == 1) {
        const int which = col >> 10, win = col & 1023;
        const float* bp = (which == 0) ? bias0 : ((which == 1) ? bias1 : bias2);
        bv = bp[win];
      } else {
        bv = bias0[col];
      }
      if (EPI == 1) {
        const int which = col >> 10, win = col & 1023;
        const int h = win >> 6, dh = win & 63;
        if (which < 2) {
#pragma unroll
          for (int r = 0; r < 4; r++) {
            const int row = row0 + wm*64 + mi*16 + lhi*4 + r;
            const int b = row >> 11, s = row & 2047;
            float v = acc[mi][ni][r] + bv;
            // fold 1/sqrt(DH) * log2(e) into Q: scores land in log2 domain
            if (which == 0) v *= 0.18033688011112042f;
            ((bf16*)Cout)[((((size_t)which*BDIM + b)*HDIM + h)*SDIM + s)*64 + dh] =
                __float2bfloat16(v);
          }
        } else {
          // V slab -> transposed [B,H,64,S]; 4 consecutive s per lane
          const int row = row0 + wm*64 + mi*16 + lhi*4;
          const int b = row >> 11, s = row & 2047;
          short4v pk;
#pragma unroll
          for (int r = 0; r < 4; r++) {
            bf16 t = __float2bfloat16(acc[mi][ni][r] + bv);
            pk[r] = *(short*)&t;
          }
          bf16* vt = (bf16*)Cout + (size_t)2*BDIM*HDIM*SDIM*64;
          *(short4v*)(vt + (((size_t)b*HDIM + h)*64 + dh)*SDIM + s) = pk;
        }
      } else {
#pragma unroll
        for (int r = 0; r < 4; r++) {
          const int row = row0 + wm*64 + mi*16 + lhi*4 + r;
          float v = acc[mi][ni][r] + bv;
          if (EPI == 0) {
            ((float*)Cout)[(size_t)row * N + col] = v;
          } else {
            // GELU tanh form via native exp2: v / (1 + 2^(-2u*log2e))
            float u  = 0.79788456080286536f * v * (1.f + 0.044715f * v * v);
            float gl = v / (1.f + EXP2F(-2.8853900817779268f * u));
            ((bf16*)Cout)[(size_t)row * N + col] = __float2bfloat16(gl);
          }
        }
      }
    }
  }
}

// ---------------------------------------------------------------------------
// Flash attention fwd. grid = (S/128, B*H), 512 threads (8 waves).
// QBLK=128, KBLK=64, double-buffered K/V staging (R9 structure, VGPR=64),
// s_setprio around MFMA clusters, packed-bit mask applied after exp2.
// Scores arrive in log2 domain (Q pre-scaled by 0.125*log2e); all exp are
// native v_exp_f32 (EXP2F).
// ---------------------------------------------------------------------------
__global__ __launch_bounds__(512)
void attn_fwd(const bf16* __restrict__ qkv,
              const unsigned long long* __restrict__ mbits,
              bf16* __restrict__ Obuf)
{
  __shared__ bf16 Ks[2][64*64];   // [buf][key][dh], swizzled slots
  __shared__ bf16 Vs[2][64*64];   // [buf][dh][key], swizzled slots
  __shared__ bf16 Ps[8][16*64];   // per-wave P tile, swizzled slots

  const int tid  = threadIdx.x;
  const int wave = tid >> 6, lane = tid & 63;
  const int llo  = lane & 15, lhi = lane >> 4;
  const int bh = blockIdx.y;
  const int b = bh >> 4, h = bh & 15;
  const int q0 = blockIdx.x * 128;

  const bf16* Qp  = qkv + ((size_t)b*HDIM + h) * (size_t)SDIM * 64;
  const bf16* Kp  = qkv + ((size_t)(BDIM*HDIM) + b*HDIM + h) * (size_t)SDIM * 64;
  const bf16* Vtp = qkv + (size_t)2*BDIM*HDIM*SDIM*64
                        + ((size_t)b*HDIM + h) * (size_t)64 * SDIM;  // [64][S]

  short8 qf[2];
  {
    const bf16* qrow = Qp + (size_t)(q0 + wave*16 + llo) * 64;
    qf[0] = *(const short8*)(qrow + lhi*8);
    qf[1] = *(const short8*)(qrow + 32 + lhi*8);
  }

  f32x4 o[4];
#pragma unroll
  for (int n = 0; n < 4; n++) o[n] = (f32x4){0.f, 0.f, 0.f, 0.f};
  float mrun[4], lrun[4];
#pragma unroll
  for (int r = 0; r < 4; r++) { mrun[r] = -INFINITY; lrun[r] = 0.f; }

  const int srow = lane >> 3;                  // row within 8-row chunk
  const int scol = ((lane & 7) ^ srow) * 8;    // pre-swizzled source col (elems)
  const size_t mrow = ((size_t)b*SDIM + q0 + wave*16 + lhi*4) * 32;
  const int sh0 = 31 - llo, sh1 = 15 - llo;    // sign-mask shift amounts

  // prologue: stage tile 0 into buffer 0
  gll16(Kp + (size_t)(wave*8 + srow)*64 + scol, &Ks[0][wave*512]);
  gll16(Vtp + (size_t)(wave*8 + srow)*SDIM + scol, &Vs[0][wave*512]);
  __syncthreads();

  for (int kt = 0; kt < SDIM/64; ++kt) {
    const int cur = kt & 1;
    // issue next tile's staging into the other buffer (latency hides under
    // this tile's compute; drained by the end-of-iteration barrier)
    if (kt + 1 < SDIM/64) {
      const int k1 = (kt + 1) * 64;
      gll16(Kp + (size_t)(k1 + wave*8 + srow)*64 + scol, &Ks[cur^1][wave*512]);
      gll16(Vtp + (size_t)(wave*8 + srow)*SDIM + k1 + scol, &Vs[cur^1][wave*512]);
    }
    // mask bits for this wave's 4 q-rows (broadcast across llo)
    unsigned mlo[4], mhi[4];
#pragma unroll
    for (int r = 0; r < 4; r++) {
      unsigned long long mw = mbits[mrow + (size_t)r*32 + kt];
      mlo[r] = (unsigned)mw; mhi[r] = (unsigned)(mw >> 32);
    }

    // S = Q K^T  (16 q-rows x 64 keys per wave), log2 domain
    float sv[4][4];
    __builtin_amdgcn_s_setprio(1);
#pragma unroll
    for (int n = 0; n < 4; n++) {
      const int krow = (n*16 + llo) * 64;
      const int sw   = llo & 7;
      short8 kf0 = *(const short8*)(&Ks[cur][krow + ((lhi ^ sw) * 8)]);
      short8 kf1 = *(const short8*)(&Ks[cur][krow + (((4 | lhi) ^ sw) * 8)]);
      f32x4 z = (f32x4){0.f, 0.f, 0.f, 0.f};
      z = mfma16(qf[0], kf0, z);
      z = mfma16(qf[1], kf1, z);
#pragma unroll
      for (int r = 0; r < 4; r++) sv[n][r] = z[r];
    }
    __builtin_amdgcn_s_setprio(0);
    // online softmax (log2 domain; masked p zeroed after exp2)
    float mnew[4], scale[4];
#pragma unroll
    for (int r = 0; r < 4; r++) {
      float rm = fmaxf(fmaxf(sv[0][r], sv[1][r]), fmaxf(sv[2][r], sv[3][r]));
      rm = fmaxf(rm, __shfl_xor(rm, 1));
      rm = fmaxf(rm, __shfl_xor(rm, 2));
      rm = fmaxf(rm, __shfl_xor(rm, 4));
      rm = fmaxf(rm, __shfl_xor(rm, 8));
      mnew[r] = fmaxf(mrun[r], rm);
      scale[r] = EXP2F(mrun[r] - mnew[r]);
      mrun[r] = mnew[r];
    }
    float rsum[4] = {0.f, 0.f, 0.f, 0.f};
#pragma unroll
    for (int n = 0; n < 4; n++)
#pragma unroll
      for (int r = 0; r < 4; r++) {
        float p = EXP2F(sv[n][r] - mnew[r]);
        const unsigned w = (n & 2) ? mhi[r] : mlo[r];
        const int sx = ((int)(w << ((n & 1) ? sh1 : sh0))) >> 31; // 0 or -1
        p = __uint_as_float(__float_as_uint(p) & (unsigned)sx);
        sv[n][r] = p;
        rsum[r] += p;
      }
#pragma unroll
    for (int r = 0; r < 4; r++) {
      float rs = rsum[r];
      rs += __shfl_xor(rs, 1);
      rs += __shfl_xor(rs, 2);
      rs += __shfl_xor(rs, 4);
      rs += __shfl_xor(rs, 8);
      lrun[r] = lrun[r]*scale[r] + rs;
    }
#pragma unroll
    for (int n = 0; n < 4; n++)
#pragma unroll
      for (int r = 0; r < 4; r++) o[n][r] *= scale[r];
    // P -> LDS (C-layout -> A-layout), swizzled slots, per-wave region
#pragma unroll
    for (int n = 0; n < 4; n++)
#pragma unroll
      for (int r = 0; r < 4; r++) {
        const int prow = lhi*4 + r;
        const int slot = (n*2 + (llo >> 3)) ^ (prow & 7);
        Ps[wave][prow*64 + slot*8 + (llo & 7)] = __float2bfloat16(sv[n][r]);
      }
    // PV
    __builtin_amdgcn_s_setprio(1);
#pragma unroll
    for (int kk = 0; kk < 2; kk++) {
      const int sl = ((kk*4 + lhi) ^ (llo & 7)) * 8;
      short8 pf = *(const short8*)(&Ps[wave][llo*64 + sl]);
#pragma unroll
      for (int n = 0; n < 4; n++) {
        short8 vf = *(const short8*)(&Vs[cur][(n*16 + llo)*64 + sl]);
        o[n] = mfma16(pf, vf, o[n]);
      }
    }
    __builtin_amdgcn_s_setprio(0);
    __syncthreads();   // drains next-tile staging; protects buffer reuse
  }

#pragma unroll
  for (int n = 0; n < 4; n++)
#pragma unroll
    for (int r = 0; r < 4; r++) {
      float v = o[n][r] / lrun[r];
      const int row = q0 + wave*16 + lhi*4 + r;
      const int col = h*64 + n*16 + llo;
      Obuf[((size_t)b*SDIM + row)*DDIM + col] = __float2bfloat16(v);
    }
}

// ---------------------------------------------------------------------------
// out = resid + LayerNorm(y)*g + b ; optional bf16 copy of out.
// One block (256 thr) per row of 1024.
// ---------------------------------------------------------------------------
template<bool WB>
__global__ __launch_bounds__(256)
void add_ln(const float* __restrict__ resid, const float* __restrict__ y,
            const float* __restrict__ gam, const float* __restrict__ bet,
            float* __restrict__ outf, bf16* __restrict__ outb)
{
  __shared__ float red[4];
  const int row = blockIdx.x;
  const int t = threadIdx.x;
  float4 v = ((const float4*)(y + (size_t)row*DDIM))[t];
  float s = v.x + v.y + v.z + v.w;
#pragma unroll
  for (int off = 1; off < 64; off <<= 1) s += __shfl_xor(s, off);
  if ((t & 63) == 0) red[t >> 6] = s;
  __syncthreads();
  const float mean = (red[0]+red[1]+red[2]+red[3]) * (1.f/DDIM);
  const float dx = v.x-mean, dy = v.y-mean, dz = v.z-mean, dw = v.w-mean;
  float sq = dx*dx + dy*dy + dz*dz + dw*dw;
#pragma unroll
  for (int off = 1; off < 64; off <<= 1) sq += __shfl_xor(sq, off);
  __syncthreads();
  if ((t & 63) == 0) red[t >> 6] = sq;
  __syncthreads();
  const float var = (red[0]+red[1]+red[2]+red[3]) * (1.f/DDIM);
  const float rst = rsqrtf(var + 1e-6f);
  const float4 g  = ((const float4*)gam)[t];
  const float4 bb = ((const float4*)bet)[t];
  const float4 rv = ((const float4*)(resid + (size_t)row*DDIM))[t];
  float4 ov;
  ov.x = rv.x + dx*rst*g.x + bb.x;
  ov.y = rv.y + dy*rst*g.y + bb.y;
  ov.z = rv.z + dz*rst*g.z + bb.z;
  ov.w = rv.w + dw*rst*g.w + bb.w;
  ((float4*)(outf + (size_t)row*DDIM))[t] = ov;
  if (WB) {
    bf16* ob = outb + (size_t)row*DDIM + t*4;
    ob[0] = __float2bfloat16(ov.x);
    ob[1] = __float2bfloat16(ov.y);
    ob[2] = __float2bfloat16(ov.z);
    ob[3] = __float2bfloat16(ov.w);
  }
}

// ---------------------------------------------------------------------------
// Prep kernels
// ---------------------------------------------------------------------------
__global__ __launch_bounds__(256)
void transpose_cast(const float* __restrict__ in, bf16* __restrict__ out,
                    int R, int C)   // out[c][r] = in[r][c]; grid (C/32, R/32)
{
  __shared__ float tile[32][33];
  const int x = threadIdx.x & 31, y = threadIdx.x >> 5;
  const int c0 = blockIdx.x * 32, r0 = blockIdx.y * 32;
#pragma unroll
  for (int i = 0; i < 32; i += 8)
    tile[y + i][x] = in[(size_t)(r0 + y + i)*C + c0 + x];
  __syncthreads();
#pragma unroll
  for (int i = 0; i < 32; i += 8)
    out[(size_t)(c0 + y + i)*R + r0 + x] = __float2bfloat16(tile[x][y + i]);
}

__global__ __launch_bounds__(256)
void cast_to_bf16(const float* __restrict__ in, bf16* __restrict__ out, int n4)
{
  const int i = blockIdx.x * 256 + threadIdx.x;
  if (i < n4) {
    float4 v = ((const float4*)in)[i];
    bf16* o = out + (size_t)i*4;
    o[0] = __float2bfloat16(v.x);
    o[1] = __float2bfloat16(v.y);
    o[2] = __float2bfloat16(v.z);
    o[3] = __float2bfloat16(v.w);
  }
}

// pack mask int32 -> 1 bit per entry; one wave per 64-entry word
__global__ __launch_bounds__(256)
void mask_bits_kernel(const int* __restrict__ mask,
                      unsigned long long* __restrict__ bits)
{
  const int wid = blockIdx.x * 4 + (threadIdx.x >> 6);
  const int lane = threadIdx.x & 63;
  const int m = mask[(size_t)wid * 64 + lane];
  const unsigned long long bal = __ballot(m != 0);
  if (lane == 0) bits[wid] = bal;
}

// ---------------------------------------------------------------------------
// Launch. Workspace layout (bytes), total 209,715,200 (~200 MB):
//   0         xb       16,777,216   [x1b aliases]
//   16777216  Wqkvt     6,291,456
//   23068672  Wot       2,097,152
//   25165824  W1t       8,388,608
//   33554432  W2t       8,388,608
//   41943040  mbits     2,097,152   [ffb (32MB) aliases 41943040..75497472]
//   75497472  qkv      50,331,648   [h1 aliases qkv+obuf; V slab = [B,H,64,S]]
//   125829120 obuf     16,777,216
//   142606336 aproj    33,554,432
//   176160768 x1f      33,554,432
// ---------------------------------------------------------------------------
extern "C" void kernel_launch(void* const* d_in, const int* in_sizes, int n_in,
                              void* d_out, int out_size, void* d_ws, size_t ws_size,
                              hipStream_t stream)
{
  (void)in_sizes; (void)n_in; (void)out_size; (void)ws_size;
  const float* x    = (const float*)d_in[0];
  const int*   mask = (const int*)d_in[1];
  const float* Wq   = (const float*)d_in[2];
  const float* bq   = (const float*)d_in[3];
  const float* Wk   = (const float*)d_in[4];
  const float* bk   = (const float*)d_in[5];
  const float* Wv   = (const float*)d_in[6];
  const float* bv   = (const float*)d_in[7];
  const float* Wo   = (const float*)d_in[8];
  const float* bo   = (const float*)d_in[9];
  const float* ln1g = (const float*)d_in[10];
  const float* ln1b = (const float*)d_in[11];
  const float* W1   = (const float*)d_in[12];
  const float* b1   = (const float*)d_in[13];
  const float* W2   = (const float*)d_in[14];
  const float* b2   = (const float*)d_in[15];
  const float* ln2g = (const float*)d_in[16];
  const float* ln2b = (const float*)d_in[17];
  float* out = (float*)d_out;

  char* ws = (char*)d_ws;
  bf16* xb    = (bf16*)(ws + 0);
  bf16* Wqkvt = (bf16*)(ws + 16777216);
  bf16* Wot   = (bf16*)(ws + 23068672);
  bf16* W1t   = (bf16*)(ws + 25165824);
  bf16* W2t   = (bf16*)(ws + 33554432);
  unsigned long long* mbits = (unsigned long long*)(ws + 41943040);
  bf16* qkv   = (bf16*)(ws + 75497472);
  bf16* obuf  = (bf16*)(ws + 125829120);
  float* aproj = (float*)(ws + 142606336);
  float* x1f   = (float*)(ws + 176160768);
  bf16* x1b = xb;             // alias (xb dead after QKV GEMM)
  bf16* h1  = qkv;            // alias over qkv+obuf (dead after O-proj)
  float* ffb = (float*)(ws + 41943040);  // alias over mbits (dead after attn)

  cast_to_bf16<<<dim3(MROWS*DDIM/4/256), 256, 0, stream>>>(x, xb, MROWS*DDIM/4);
  transpose_cast<<<dim3(32, 32), 256, 0, stream>>>(Wq, Wqkvt, 1024, 1024);
  transpose_cast<<<dim3(32, 32), 256, 0, stream>>>(Wk, Wqkvt + 1024*1024, 1024, 1024);
  transpose_cast<<<dim3(32, 32), 256, 0, stream>>>(Wv, Wqkvt + 2*1024*1024, 1024, 1024);
  transpose_cast<<<dim3(32, 32), 256, 0, stream>>>(Wo, Wot, 1024, 1024);
  transpose_cast<<<dim3(FFDIM/32, 32), 256, 0, stream>>>(W1, W1t, 1024, FFDIM);
  transpose_cast<<<dim3(32, FFDIM/32), 256, 0, stream>>>(W2, W2t, FFDIM, 1024);
  mask_bits_kernel<<<dim3(BDIM*SDIM*SDIM/64/4), 256, 0, stream>>>(mask, mbits);

  // QKV projection: [8192,1024] x [1024,3072]; Q pre-scaled, V transposed
  gemm_bt<1><<<dim3(3072/128, MROWS/128), 256, 0, stream>>>(
      xb, Wqkvt, bq, bk, bv, qkv, 1024, 3072);
  // attention (QBLK=128, 8 waves, double-buffered staging)
  attn_fwd<<<dim3(SDIM/128, BDIM*HDIM), 512, 0, stream>>>(qkv, mbits, obuf);
  // O projection -> fp32
  gemm_bt<0><<<dim3(1024/128, MROWS/128), 256, 0, stream>>>(
      obuf, Wot, bo, nullptr, nullptr, aproj, 1024, 1024);
  // x1 = x + LN(attn_out); also bf16 copy for FFN
  add_ln<true><<<dim3(MROWS), 256, 0, stream>>>(x, aproj, ln1g, ln1b, x1f, x1b);
  // FFN1 + GELU -> bf16
  gemm_bt<2><<<dim3(FFDIM/128, MROWS/128), 256, 0, stream>>>(
      x1b, W1t, b1, nullptr, nullptr, h1, 1024, FFDIM);
  // FFN2 -> fp32
  gemm_bt<0><<<dim3(1024/128, MROWS/128), 256, 0, stream>>>(
      h1, W2t, b2, nullptr, nullptr, ffb, FFDIM, 1024);
  // out = x1 + LN(ff)
  add_ln<false><<<dim3(MROWS), 256, 0, stream>>>(x1f, ffb, ln2g, ln2b, out, nullptr);
}